// Round 11
// baseline (282.286 us; speedup 1.0000x reference)
//
#include <hip/hip_runtime.h>
#include <hip/hip_bf16.h>
#include <math.h>

#define B_SZ 8192
#define I_SZ 1024
#define O_SZ 1024
#define NCP  6

typedef __attribute__((ext_vector_type(8))) short bf16x8;
typedef __attribute__((ext_vector_type(4))) float f32x4;

__device__ __forceinline__ unsigned short f2bf(float f) {
  union { float f; unsigned int u; } v; v.f = f;
  unsigned int u = v.u;
  u += 0x7FFFu + ((u >> 16) & 1u);   // round-to-nearest-even
  return (unsigned short)(u >> 16);
}

__global__ void cvt_f32_to_bf16(const float* __restrict__ src,
                                unsigned short* __restrict__ dst, int n4) {
  int idx = blockIdx.x * blockDim.x + threadIdx.x;
  int stride = gridDim.x * blockDim.x;
  for (int i = idx; i < n4; i += stride) {
    float4 v = reinterpret_cast<const float4*>(src)[i];
    ushort4 o;
    o.x = f2bf(v.x); o.y = f2bf(v.y); o.z = f2bf(v.z); o.w = f2bf(v.w);
    reinterpret_cast<ushort4*>(dst)[i] = o;
  }
}

__device__ __forceinline__ void gload_lds16(const void* g, void* l) {
  __builtin_amdgcn_global_load_lds(
      (const __attribute__((address_space(1))) void*)g,
      (__attribute__((address_space(3))) void*)l, 16, 0, 0);
}

#define BM 256
#define BN 128
#define BK 64
#define NT 96    // 6 j-chunks x 16 K-tiles, j = t>>4, ks = t&15

// out[b,o] = sum_j c[b,j] * ( sum_i W[j,o,i]*x[b,i] + bias[j,o] )
// Round-8 structure (j-outer, part[] as pure-MFMA AGPR chain, fold once per
// 16 tiles -- the register discipline that ran with ZERO scratch traffic)
// with ONE change: A-fragments come DIRECTLY from global (L2-resident; each
// XCD's blocks share 4 x 32KB A-slabs) instead of through LDS. LDS now
// carries only the W ring (3 x 16KB, gload_lds linear dest + pre-swizzled
// source + XOR'd ds_read, rule #21) -- halves the LDS-pipe load and lets
// the A traffic ride the parallel VMEM pipe.
// vmcnt ledger: per tile afr(8 VMEM) issued FIRST, then W(t+2)(2 DMA);
// compiler's afr wait = vmcnt(2) leaves the DMAs in flight; end-of-tile
// vmcnt(2) (tail: 0) + s_barrier => W(t+1) resident for next tile.
__global__ __launch_bounds__(512, 2) void pfl_gemm(
    const unsigned short* __restrict__ xb,
    const unsigned short* __restrict__ wb,
    const float* __restrict__ phase,
    const float* __restrict__ bias,
    float* __restrict__ out) {
  __shared__ __align__(16) unsigned short Wbuf[3][BN * BK];  // 3x16 KB
  __shared__ __align__(16) float c4[NCP][BM];                // 6 KB

  const int nbn = O_SZ / BN;  // 8
  int bid = (int)blockIdx.x;  // 256 blocks (divisible by 8)
  int swz = (bid & 7) * 32 + (bid >> 3);  // bijective XCD remap
  int brow = (swz / nbn) * BM;
  int bcol = (swz % nbn) * BN;

  int tid = (int)threadIdx.x;
  int lane = tid & 63;
  int wid = tid >> 6;        // 0..7
  int wr = wid >> 1;         // 0..3 (M)
  int wc = wid & 1;          // 0..1 (N)

  // ---- Catmull-Rom coefficients, layout [j][row] for vectorized folds ----
  if (tid < BM) {
    float ph = phase[brow + tid];
    const float two_pi = 6.2831855f;
    float pm = fmodf(ph, two_pi);              // ph >= 0 -> trunc == floor mod
    float pos = pm * (float)(6.0 / 6.283185307179586);
    float base = floorf(pos);
    int bi = (int)base;
    float t = pos - base;
    float t2 = t * t, t3 = t2 * t;
    float w0 = -0.5f * t + t2 - 0.5f * t3;
    float w1 = 1.0f - 2.5f * t2 + 1.5f * t3;
    float w2 = 0.5f * t + 2.0f * t2 - 1.5f * t3;
    float w3 = -0.5f * t2 + 0.5f * t3;
    float cc[NCP] = {0.f, 0.f, 0.f, 0.f, 0.f, 0.f};
    cc[((bi - 1) % NCP + NCP) % NCP] += w0;
    cc[(bi % NCP + NCP) % NCP]       += w1;
    cc[((bi + 1) % NCP + NCP) % NCP] += w2;
    cc[((bi + 2) % NCP + NCP) % NCP] += w3;
    for (int j = 0; j < NCP; ++j) c4[j][tid] = cc[j];
  }

  f32x4 acc[4][4];   // folded result (cold; VALU-touched every 16 tiles)
  f32x4 part[4][4];  // pure MFMA chain within a j-chunk (AGPR-resident)
#pragma unroll
  for (int m = 0; m < 4; ++m)
#pragma unroll
    for (int n = 0; n < 4; ++n) {
      acc[m][n] = (f32x4){0.f, 0.f, 0.f, 0.f};
      part[m][n] = (f32x4){0.f, 0.f, 0.f, 0.f};
    }

  // W staging: lane l -> LDS row (base + l>>3), linear 16B slot (l&7);
  // global source column pre-swizzled (slot xor row&7), rule #21.
  int swzcol = ((lane & 7) ^ (lane >> 3)) * 8;
  const unsigned short* wsrc =
      wb + (size_t)(bcol + wid * 8 + (lane >> 3)) * I_SZ + swzcol;
  // read-side swizzled base: slot = k-chunk ^ (row&7); row&7 == lane&7 here
  int lbase = (lane & 15) * 128 + (((lane >> 4) ^ (lane & 7)) & 7) * 16;

  // A direct-global per-lane base: row = brow + wr*64 + m*16 + (lane&15),
  // k = (t&15)*64 + kk*32 + (lane>>4)*8   (xb linear, no swizzle)
  const unsigned short* xA =
      xb + (size_t)(brow + wr * 64 + (lane & 15)) * I_SZ + (lane >> 4) * 8;

  auto STAGE_W = [&](int g, int slot) {   // g = global tile index
    const unsigned short* ws =
        wsrc + (size_t)(g >> 4) * O_SZ * I_SZ + (g & 15) * BK;
#pragma unroll
    for (int p = 0; p < 2; ++p)
      gload_lds16(ws + (size_t)p * 64 * I_SZ,
                  &Wbuf[slot][(wid * 8 + p * 64) * BK]);
  };

  // prologue: W0, W1 in flight; W0 resident; c4 published
  STAGE_W(0, 0);
  STAGE_W(1, 1);
  asm volatile("s_waitcnt vmcnt(2)" ::: "memory");
  __builtin_amdgcn_sched_barrier(0);
  __syncthreads();

  int cur = 0;
  for (int t = 0; t < NT; ++t) {
    const char* Wl = (const char*)&Wbuf[cur][0];
    int st = cur + 2; if (st >= 3) st -= 3;
    const int pre = (t + 2 < NT);

    // ---- A fragments: direct global (issued first => compiler waits
    //      vmcnt(2), leaving the W DMAs in flight) ----
    bf16x8 afr[4][2];
    const unsigned short* xAk = xA + ((t & 15) << 6);
#pragma unroll
    for (int m = 0; m < 4; ++m)
#pragma unroll
      for (int kk = 0; kk < 2; ++kk)
        afr[m][kk] = *reinterpret_cast<const bf16x8*>(
            xAk + (size_t)m * 16 * I_SZ + kk * 32);
    if (pre) STAGE_W(t + 2, st);   // slot st last read at t-1, safe
    __builtin_amdgcn_sched_barrier(0);

    bf16x8 bfr[4];

    // ================= phase 0 (kk = 0) =================
#pragma unroll
    for (int n = 0; n < 4; ++n)
      bfr[n] = *reinterpret_cast<const bf16x8*>(
          Wl + (wc * 64 + n * 16) * 128 + lbase);
    __builtin_amdgcn_s_barrier();
    asm volatile("s_waitcnt lgkmcnt(0)" ::: "memory");
    __builtin_amdgcn_sched_barrier(0);
    __builtin_amdgcn_s_setprio(1);
#pragma unroll
    for (int m = 0; m < 4; ++m)
#pragma unroll
      for (int n = 0; n < 4; ++n)
        part[m][n] = __builtin_amdgcn_mfma_f32_16x16x32_bf16(
            afr[m][0], bfr[n], part[m][n], 0, 0, 0);
    __builtin_amdgcn_s_setprio(0);
    __builtin_amdgcn_s_barrier();

    // ================= phase 1 (kk = 1) =================
#pragma unroll
    for (int n = 0; n < 4; ++n)
      bfr[n] = *reinterpret_cast<const bf16x8*>(
          Wl + (wc * 64 + n * 16) * 128 + (lbase ^ 64));
    if (pre)
      asm volatile("s_waitcnt vmcnt(2)" ::: "memory");  // W(t+1) resident
    else
      asm volatile("s_waitcnt vmcnt(0)" ::: "memory");
    __builtin_amdgcn_sched_barrier(0);
    __builtin_amdgcn_s_barrier();
    asm volatile("s_waitcnt lgkmcnt(0)" ::: "memory");
    __builtin_amdgcn_sched_barrier(0);
    __builtin_amdgcn_s_setprio(1);
#pragma unroll
    for (int m = 0; m < 4; ++m)
#pragma unroll
      for (int n = 0; n < 4; ++n)
        part[m][n] = __builtin_amdgcn_mfma_f32_16x16x32_bf16(
            afr[m][1], bfr[n], part[m][n], 0, 0, 0);
    __builtin_amdgcn_s_setprio(0);

    if ((t & 15) == 15) {  // j-chunk boundary: acc += c[row,j] * part
      int j = t >> 4;
#pragma unroll
      for (int m = 0; m < 4; ++m) {
        f32x4 cv = *reinterpret_cast<const f32x4*>(
            &c4[j][wr * 64 + m * 16 + (lane >> 4) * 4]);
#pragma unroll
        for (int n = 0; n < 4; ++n) {
          acc[m][n] += cv * part[m][n];
          part[m][n] = (f32x4){0.f, 0.f, 0.f, 0.f};
        }
      }
    }
    __builtin_amdgcn_s_barrier();
    ++cur; if (cur == 3) cur = 0;
  }

  // ---- epilogue: bias mix + store (f32) ----
#pragma unroll
  for (int n = 0; n < 4; ++n) {
    int col = bcol + wc * 64 + n * 16 + (lane & 15);
    float b6[NCP];
#pragma unroll
    for (int j = 0; j < NCP; ++j) b6[j] = bias[j * O_SZ + col];
#pragma unroll
    for (int m = 0; m < 4; ++m) {
#pragma unroll
      for (int r = 0; r < 4; ++r) {
        int rloc = wr * 64 + m * 16 + (lane >> 4) * 4 + r;
        float s = 0.f;
#pragma unroll
        for (int j = 0; j < NCP; ++j) s += c4[j][rloc] * b6[j];
        out[(size_t)(brow + rloc) * O_SZ + col] = acc[m][n][r] + s;
      }
    }
  }
}

extern "C" void kernel_launch(void* const* d_in, const int* in_sizes, int n_in,
                              void* d_out, int out_size, void* d_ws, size_t ws_size,
                              hipStream_t stream) {
  (void)in_sizes; (void)n_in; (void)out_size; (void)ws_size;
  const float* x     = (const float*)d_in[0];  // [B, I]
  const float* phase = (const float*)d_in[1];  // [B]
  const float* w     = (const float*)d_in[2];  // [C, O, I]
  const float* bias  = (const float*)d_in[3];  // [C, O]
  float* out = (float*)d_out;                  // [B, O] f32

  unsigned short* xb = (unsigned short*)d_ws;                       // 16 MB
  unsigned short* wb = (unsigned short*)((char*)d_ws +
                        (size_t)B_SZ * I_SZ * sizeof(unsigned short));  // 12 MB

  cvt_f32_to_bf16<<<2048, 256, 0, stream>>>(x, xb, B_SZ * I_SZ / 4);
  cvt_f32_to_bf16<<<1536, 256, 0, stream>>>(w, wb, NCP * O_SZ * I_SZ / 4);

  dim3 grid((B_SZ / BM) * (O_SZ / BN));  // 32*8 = 256
  pfl_gemm<<<grid, 512, 0, stream>>>(xb, wb, phase, bias, out);
}

// Round 12
// 123.220 us; speedup vs baseline: 2.2909x; 2.2909x over previous
//
#include <hip/hip_runtime.h>
#include <hip/hip_bf16.h>
#include <math.h>

#define B_SZ 8192
#define I_SZ 1024
#define O_SZ 1024
#define NCP  6

typedef __attribute__((ext_vector_type(8))) short bf16x8;
typedef __attribute__((ext_vector_type(4))) float f32x4;

__device__ __forceinline__ unsigned short f2bf(float f) {
  union { float f; unsigned int u; } v; v.f = f;
  unsigned int u = v.u;
  u += 0x7FFFu + ((u >> 16) & 1u);   // round-to-nearest-even
  return (unsigned short)(u >> 16);
}

__global__ void cvt_f32_to_bf16(const float* __restrict__ src,
                                unsigned short* __restrict__ dst, int n4) {
  int idx = blockIdx.x * blockDim.x + threadIdx.x;
  int stride = gridDim.x * blockDim.x;
  for (int i = idx; i < n4; i += stride) {
    float4 v = reinterpret_cast<const float4*>(src)[i];
    ushort4 o;
    o.x = f2bf(v.x); o.y = f2bf(v.y); o.z = f2bf(v.z); o.w = f2bf(v.w);
    reinterpret_cast<ushort4*>(dst)[i] = o;
  }
}

__device__ __forceinline__ void gload_lds16(const void* g, void* l) {
  __builtin_amdgcn_global_load_lds(
      (const __attribute__((address_space(1))) void*)g,
      (__attribute__((address_space(3))) void*)l, 16, 0, 0);
}

#define BM 256
#define BN 128
#define BK 64
#define NT 96    // 6 j-chunks x 16 K-tiles
#define NBUF 3   // depth-2 prefetch: stage t+2 while computing t

// out[b,o] = sum_j c[b,j] * ( sum_i W[j,o,i]*x[b,i] + bias[j,o] )
// Round-8 memory structure (A+B through LDS-DMA ring-3, both-sides XOR
// swizzle, part[] AGPR chain folded per j-chunk -- verified 128us) with the
// tile BODY reworked: register-double-buffered fragments + ONE barrier per
// tile (R8 had 4). Per tile:
//   read kk0 frags | STAGE(t+2) | lgkm(0) | issue kk1 frag reads (fly under
//   MFMA0) | MFMA0 | lgkm(0) | MFMA1 | [fold] | vmcnt(6) | s_barrier
// kk1 ds_reads overlap MFMA0 within-wave (no barrier between); counted
// vmcnt keeps 6 DMAs in flight ACROSS the barrier; barriers 384 -> 96.
// Ring ledger: slot st=cur+2 last read at t-1 (ordered by t-1's barrier);
// at t's vmcnt(6), outstanding = t+1's 6 + t+2's 6 -> oldest 6 (t+1) land.
__global__ __launch_bounds__(512, 1) void pfl_gemm(
    const unsigned short* __restrict__ xb,
    const unsigned short* __restrict__ wb,
    const float* __restrict__ phase,
    const float* __restrict__ bias,
    float* __restrict__ out) {
  __shared__ __align__(16) unsigned short Abuf[NBUF][BM * BK];  // 3x32 KB
  __shared__ __align__(16) unsigned short Bbuf[NBUF][BN * BK];  // 3x16 KB
  __shared__ __align__(16) float c4[NCP][BM];                   // 6 KB

  const int nbn = O_SZ / BN;  // 8
  int bid = (int)blockIdx.x;  // 256 blocks (divisible by 8)
  int swz = (bid & 7) * 32 + (bid >> 3);  // bijective XCD remap
  int brow = (swz / nbn) * BM;
  int bcol = (swz % nbn) * BN;

  int tid = (int)threadIdx.x;
  int lane = tid & 63;
  int wid = tid >> 6;        // 0..7
  int wr = wid >> 1;         // 0..3 (M)
  int wc = wid & 1;          // 0..1 (N)

  // ---- Catmull-Rom coefficients, layout [j][row] for vectorized folds ----
  if (tid < BM) {
    float ph = phase[brow + tid];
    const float two_pi = 6.2831855f;
    float pm = fmodf(ph, two_pi);              // ph >= 0 -> trunc == floor mod
    float pos = pm * (float)(6.0 / 6.283185307179586);
    float base = floorf(pos);
    int bi = (int)base;
    float t = pos - base;
    float t2 = t * t, t3 = t2 * t;
    float w0 = -0.5f * t + t2 - 0.5f * t3;
    float w1 = 1.0f - 2.5f * t2 + 1.5f * t3;
    float w2 = 0.5f * t + 2.0f * t2 - 1.5f * t3;
    float w3 = -0.5f * t2 + 0.5f * t3;
    float cc[NCP] = {0.f, 0.f, 0.f, 0.f, 0.f, 0.f};
    cc[((bi - 1) % NCP + NCP) % NCP] += w0;
    cc[(bi % NCP + NCP) % NCP]       += w1;
    cc[((bi + 1) % NCP + NCP) % NCP] += w2;
    cc[((bi + 2) % NCP + NCP) % NCP] += w3;
    for (int j = 0; j < NCP; ++j) c4[j][tid] = cc[j];
  }

  f32x4 acc[4][4];   // folded result (VALU-touched once per 16 tiles)
  f32x4 part[4][4];  // pure MFMA chain within a j-chunk (AGPR-resident)
#pragma unroll
  for (int m = 0; m < 4; ++m)
#pragma unroll
    for (int n = 0; n < 4; ++n) {
      acc[m][n] = (f32x4){0.f, 0.f, 0.f, 0.f};
      part[m][n] = (f32x4){0.f, 0.f, 0.f, 0.f};
    }

  // staging: lane l -> LDS row (8-group + l>>3), linear 16B slot (l&7);
  // global source column pre-swizzled (slot xor row&7), rule #21.
  int swzcol = ((lane & 7) ^ (lane >> 3)) * 8;
  const unsigned short* xsrc =
      xb + (size_t)(brow + wid * 8 + (lane >> 3)) * I_SZ + swzcol;
  const unsigned short* wsrc =
      wb + (size_t)(bcol + wid * 8 + (lane >> 3)) * I_SZ + swzcol;

  // read-side swizzled base: slot = chunk ^ (row&7); row&7 == lane&7 here
  int lbase = (lane & 15) * 128 + (((lane >> 4) ^ (lane & 7)) & 7) * 16;

  auto STAGE = [&](int t, int b) {   // 6 DMAs: 4 A + 2 B
    int ks = (t & 15) * 64;
    int j = t >> 4;
    const unsigned short* xs = xsrc + ks;
    const unsigned short* ws = wsrc + (size_t)j * O_SZ * I_SZ + ks;
    unsigned short* Ad = &Abuf[b][(wid * 8) * BK];
    unsigned short* Bd = &Bbuf[b][(wid * 8) * BK];
#pragma unroll
    for (int p = 0; p < 4; ++p)
      gload_lds16(xs + (size_t)p * 64 * I_SZ, Ad + p * 64 * BK);
#pragma unroll
    for (int p = 0; p < 2; ++p)
      gload_lds16(ws + (size_t)p * 64 * I_SZ, Bd + p * 64 * BK);
  };

  // prologue: tiles 0,1 in flight (12 DMAs); tile 0 resident; c4 published
  STAGE(0, 0);
  STAGE(1, 1);
  asm volatile("s_waitcnt vmcnt(6)" ::: "memory");
  __builtin_amdgcn_sched_barrier(0);
  __syncthreads();

  int cur = 0;
  for (int t = 0; t < NT; ++t) {
    const char* Ab = (const char*)&Abuf[cur][0];
    const char* Bb = (const char*)&Bbuf[cur][0];
    int st = cur + 2; if (st >= NBUF) st -= NBUF;

    // ---- kk=0 fragment reads ----
    bf16x8 af0[4], bf0[4], af1[4], bf1[4];
#pragma unroll
    for (int m = 0; m < 4; ++m)
      af0[m] = *reinterpret_cast<const bf16x8*>(
          Ab + (wr * 64 + m * 16) * 128 + lbase);
#pragma unroll
    for (int n = 0; n < 4; ++n)
      bf0[n] = *reinterpret_cast<const bf16x8*>(
          Bb + (wc * 64 + n * 16) * 128 + lbase);
    // ---- stage t+2 (vmcnt ops; do not disturb lgkm) ----
    if (t + 2 < NT) STAGE(t + 2, st);
    asm volatile("s_waitcnt lgkmcnt(0)" ::: "memory");
    __builtin_amdgcn_sched_barrier(0);

    // ---- issue kk=1 reads: they fly under MFMA0 ----
#pragma unroll
    for (int m = 0; m < 4; ++m)
      af1[m] = *reinterpret_cast<const bf16x8*>(
          Ab + (wr * 64 + m * 16) * 128 + (lbase ^ 64));
#pragma unroll
    for (int n = 0; n < 4; ++n)
      bf1[n] = *reinterpret_cast<const bf16x8*>(
          Bb + (wc * 64 + n * 16) * 128 + (lbase ^ 64));
    __builtin_amdgcn_sched_barrier(0);  // pin kk1 issue before MFMA0

    __builtin_amdgcn_s_setprio(1);
#pragma unroll
    for (int m = 0; m < 4; ++m)
#pragma unroll
      for (int n = 0; n < 4; ++n)
        part[m][n] = __builtin_amdgcn_mfma_f32_16x16x32_bf16(
            af0[m], bf0[n], part[m][n], 0, 0, 0);
    __builtin_amdgcn_s_setprio(0);

    asm volatile("s_waitcnt lgkmcnt(0)" ::: "memory");  // kk1 frags landed
    __builtin_amdgcn_sched_barrier(0);

    __builtin_amdgcn_s_setprio(1);
#pragma unroll
    for (int m = 0; m < 4; ++m)
#pragma unroll
      for (int n = 0; n < 4; ++n)
        part[m][n] = __builtin_amdgcn_mfma_f32_16x16x32_bf16(
            af1[m], bf1[n], part[m][n], 0, 0, 0);
    __builtin_amdgcn_s_setprio(0);

    if ((t & 15) == 15) {  // j-chunk boundary: acc += c[row,j] * part
      int j = t >> 4;
#pragma unroll
      for (int m = 0; m < 4; ++m) {
        f32x4 cv = *reinterpret_cast<const f32x4*>(
            &c4[j][wr * 64 + m * 16 + (lane >> 4) * 4]);
#pragma unroll
        for (int n = 0; n < 4; ++n) {
          acc[m][n] += cv * part[m][n];
          part[m][n] = (f32x4){0.f, 0.f, 0.f, 0.f};
        }
      }
    }

    // ---- tile boundary: counted vmcnt + SINGLE barrier ----
    if (t + 2 < NT)
      asm volatile("s_waitcnt vmcnt(6)" ::: "memory");   // t+1 resident
    else
      asm volatile("s_waitcnt vmcnt(0)" ::: "memory");
    __builtin_amdgcn_sched_barrier(0);
    __builtin_amdgcn_s_barrier();
    ++cur; if (cur == NBUF) cur = 0;
  }

  // ---- epilogue: bias mix + store (f32) ----
#pragma unroll
  for (int n = 0; n < 4; ++n) {
    int col = bcol + wc * 64 + n * 16 + (lane & 15);
    float b6[NCP];
#pragma unroll
    for (int j = 0; j < NCP; ++j) b6[j] = bias[j * O_SZ + col];
#pragma unroll
    for (int m = 0; m < 4; ++m) {
#pragma unroll
      for (int r = 0; r < 4; ++r) {
        int rloc = wr * 64 + m * 16 + (lane >> 4) * 4 + r;
        float s = 0.f;
#pragma unroll
        for (int j = 0; j < NCP; ++j) s += c4[j][rloc] * b6[j];
        out[(size_t)(brow + rloc) * O_SZ + col] = acc[m][n][r] + s;
      }
    }
  }
}

extern "C" void kernel_launch(void* const* d_in, const int* in_sizes, int n_in,
                              void* d_out, int out_size, void* d_ws, size_t ws_size,
                              hipStream_t stream) {
  (void)in_sizes; (void)n_in; (void)out_size; (void)ws_size;
  const float* x     = (const float*)d_in[0];  // [B, I]
  const float* phase = (const float*)d_in[1];  // [B]
  const float* w     = (const float*)d_in[2];  // [C, O, I]
  const float* bias  = (const float*)d_in[3];  // [C, O]
  float* out = (float*)d_out;                  // [B, O] f32

  unsigned short* xb = (unsigned short*)d_ws;                       // 16 MB
  unsigned short* wb = (unsigned short*)((char*)d_ws +
                        (size_t)B_SZ * I_SZ * sizeof(unsigned short));  // 12 MB

  cvt_f32_to_bf16<<<2048, 256, 0, stream>>>(x, xb, B_SZ * I_SZ / 4);
  cvt_f32_to_bf16<<<1536, 256, 0, stream>>>(w, wb, NCP * O_SZ * I_SZ / 4);

  dim3 grid((B_SZ / BM) * (O_SZ / BN));  // 32*8 = 256
  pfl_gemm<<<grid, 512, 0, stream>>>(xb, wb, phase, bias, out);
}